// Round 1
// baseline (1395.148 us; speedup 1.0000x reference)
//
#include <hip/hip_runtime.h>
#include <hip/hip_bf16.h>
#include <math.h>

#define NROWS 524288
#define BLK 256

// Path normalization constants:
//  alpha0 = sqrt(1/384), alpha1 = alpha2 = sqrt(3/384)
//  C000 = alpha0 * 1
//  C110 = alpha0 / sqrt(3)           (paths (1,1,0),(2,2,0))
//  C1X  = alpha1 / sqrt(3) = sqrt(1/384)  (paths (0,1,1),(1,0,1),(0,2,2),(2,0,2))
//  CEPS = alpha1 / sqrt(6)           (cross paths (1,2,1),(2,1,1),(1,1,2),(2,2,2))
#define C000 0.051031036307982884f
#define C110 0.029462782549439483f
#define C1X  0.051031036307982884f
#define CEPS 0.036084391824351615f

__device__ __forceinline__ unsigned short f2b(float f) {
    union { float f; unsigned int u; } c; c.f = f;
    unsigned int u = c.u;
    unsigned int r = (u + 0x7fffu + ((u >> 16) & 1u)) >> 16;  // round-nearest-even
    return (unsigned short)r;
}
__device__ __forceinline__ float b2f(unsigned short u) {
    union { unsigned int u; float f; } c; c.u = ((unsigned int)u) << 16;
    return c.f;
}
__device__ __forceinline__ float sigm(float v) { return 1.0f / (1.0f + __expf(-v)); }

// LDS layout (transposed, bf16): element e of row t at lds[e*BLK + t].
//  h0: e=0..15   h1: e=16+u*3+i   h2: e=40+u*3+i
//  a0: e=64..79  a1: e=80+v*3+i   a2: e=104+v*3+i
__global__ __launch_bounds__(BLK) void e3nn_fwd(
    const float* __restrict__ x,
    const float* __restrict__ lw0, const float* __restrict__ lw1, const float* __restrict__ lw2,
    const float* __restrict__ aw0, const float* __restrict__ aw1, const float* __restrict__ aw2,
    const float* __restrict__ t000, const float* __restrict__ t110, const float* __restrict__ t220,
    const float* __restrict__ t011, const float* __restrict__ t101, const float* __restrict__ t121,
    const float* __restrict__ t211, const float* __restrict__ t022, const float* __restrict__ t202,
    const float* __restrict__ t112, const float* __restrict__ t222,
    float* __restrict__ out)
{
    __shared__ unsigned short lds[128 * BLK];
    const int t = threadIdx.x;
    const long n = (long)blockIdx.x * BLK + t;
    const float* xr = x + n * 64;

    // ---------------- phase 1: h / a -> LDS ----------------
    // l=0 block (mul=16), x[0:16]
    {
        float xv[16];
        #pragma unroll
        for (int i = 0; i < 4; ++i) {
            float4 v = ((const float4*)xr)[i];
            xv[4*i] = v.x; xv[4*i+1] = v.y; xv[4*i+2] = v.z; xv[4*i+3] = v.w;
        }
        float hv[16], av[16];
        #pragma unroll
        for (int v = 0; v < 16; ++v) { hv[v] = 0.f; av[v] = 0.f; }
        #pragma unroll
        for (int u = 0; u < 16; ++u) {
            #pragma unroll
            for (int v = 0; v < 16; ++v) {
                hv[v] += xv[u] * lw0[u*16+v];
                av[v] += xv[u] * aw0[u*16+v];
            }
        }
        #pragma unroll
        for (int v = 0; v < 16; ++v) {
            lds[v*BLK + t] = f2b(hv[v] * 0.25f);            // 1/sqrt(16)
            float a = av[v] * 0.25f;
            float nrm = fabsf(a);
            float den = (nrm == 0.f) ? 1.f : nrm;
            lds[(64+v)*BLK + t] = f2b(a * (sigm(nrm) / den));
        }
    }
    // l=1 blocks (mul=8): block1 x[16:40], block2 x[40:64]
    #pragma unroll 1
    for (int blk = 0; blk < 2; ++blk) {
        const float* xb = xr + 16 + blk*24;
        const float* lw = blk ? lw2 : lw1;
        const float* aw = blk ? aw2 : aw1;
        const int eh = 16 + blk*24;
        const int ea = 80 + blk*24;
        float xv[24];
        #pragma unroll
        for (int i = 0; i < 6; ++i) {
            float4 v = ((const float4*)xb)[i];
            xv[4*i] = v.x; xv[4*i+1] = v.y; xv[4*i+2] = v.z; xv[4*i+3] = v.w;
        }
        float hv[24], av[24];
        #pragma unroll
        for (int j = 0; j < 24; ++j) { hv[j] = 0.f; av[j] = 0.f; }
        #pragma unroll
        for (int u = 0; u < 8; ++u) {
            #pragma unroll
            for (int v = 0; v < 8; ++v) {
                float w1 = lw[u*8+v], w2 = aw[u*8+v];
                #pragma unroll
                for (int i = 0; i < 3; ++i) {
                    hv[v*3+i] += xv[u*3+i] * w1;
                    av[v*3+i] += xv[u*3+i] * w2;
                }
            }
        }
        const float s = 0.35355339059327373f;  // 1/sqrt(8)
        #pragma unroll
        for (int v = 0; v < 8; ++v) {
            lds[(eh+v*3+0)*BLK + t] = f2b(hv[v*3+0] * s);
            lds[(eh+v*3+1)*BLK + t] = f2b(hv[v*3+1] * s);
            lds[(eh+v*3+2)*BLK + t] = f2b(hv[v*3+2] * s);
            float a0 = av[v*3+0]*s, a1 = av[v*3+1]*s, a2 = av[v*3+2]*s;
            float nrm = sqrtf(a0*a0 + a1*a1 + a2*a2);
            float den = (nrm == 0.f) ? 1.f : nrm;
            float fac = sigm(nrm) / den;
            lds[(ea+v*3+0)*BLK + t] = f2b(a0 * fac);
            lds[(ea+v*3+1)*BLK + t] = f2b(a1 * fac);
            lds[(ea+v*3+2)*BLK + t] = f2b(a2 * fac);
        }
    }
    __syncthreads();

    #define LD(e) b2f(lds[(e)*BLK + t])

    // ---------------- phase 2: tensor-product paths ----------------
    // ---- out irrep 0 (16x0e) ----
    {
        float o0[16];
        #pragma unroll
        for (int w = 0; w < 16; ++w) o0[w] = 0.f;
        // (0,0,0)
        #pragma unroll 1
        for (int u = 0; u < 16; ++u) {
            float hu = C000 * LD(u);
            #pragma unroll 1
            for (int v = 0; v < 16; ++v) {
                float p = hu * LD(64+v);
                const float* W = t000 + (u*16+v)*16;
                #pragma unroll
                for (int w = 0; w < 16; ++w) o0[w] += p * W[w];
            }
        }
        // (1,1,0)
        #pragma unroll 1
        for (int u = 0; u < 8; ++u) {
            float hx = LD(16+u*3), hy = LD(16+u*3+1), hz = LD(16+u*3+2);
            #pragma unroll 1
            for (int v = 0; v < 8; ++v) {
                float p = C110 * (hx*LD(80+v*3) + hy*LD(80+v*3+1) + hz*LD(80+v*3+2));
                const float* W = t110 + (u*8+v)*16;
                #pragma unroll
                for (int w = 0; w < 16; ++w) o0[w] += p * W[w];
            }
        }
        // (2,2,0)
        #pragma unroll 1
        for (int u = 0; u < 8; ++u) {
            float hx = LD(40+u*3), hy = LD(40+u*3+1), hz = LD(40+u*3+2);
            #pragma unroll 1
            for (int v = 0; v < 8; ++v) {
                float p = C110 * (hx*LD(104+v*3) + hy*LD(104+v*3+1) + hz*LD(104+v*3+2));
                const float* W = t220 + (u*8+v)*16;
                #pragma unroll
                for (int w = 0; w < 16; ++w) o0[w] += p * W[w];
            }
        }
        float4* o4 = (float4*)(out + n*64);
        #pragma unroll
        for (int i = 0; i < 4; ++i) {
            float4 v; v.x = o0[4*i]; v.y = o0[4*i+1]; v.z = o0[4*i+2]; v.w = o0[4*i+3];
            o4[i] = v;
        }
    }
    // ---- out irrep 1 (8x1o) ----
    {
        float o1[24];
        #pragma unroll
        for (int j = 0; j < 24; ++j) o1[j] = 0.f;
        // (0,1,1): q[k] = C1X * h0[u] * a1[v][k]
        #pragma unroll 1
        for (int u = 0; u < 16; ++u) {
            float hu = C1X * LD(u);
            #pragma unroll 1
            for (int v = 0; v < 8; ++v) {
                float q0 = hu*LD(80+v*3), q1 = hu*LD(80+v*3+1), q2 = hu*LD(80+v*3+2);
                const float* W = t011 + (u*8+v)*8;
                #pragma unroll
                for (int w = 0; w < 8; ++w) {
                    float ww = W[w];
                    o1[w*3+0] += q0*ww; o1[w*3+1] += q1*ww; o1[w*3+2] += q2*ww;
                }
            }
        }
        // (1,0,1): q[k] = C1X * h1[u][k] * a0[v]
        #pragma unroll 1
        for (int u = 0; u < 8; ++u) {
            float hx = LD(16+u*3), hy = LD(16+u*3+1), hz = LD(16+u*3+2);
            #pragma unroll 1
            for (int v = 0; v < 16; ++v) {
                float a = C1X * LD(64+v);
                float q0 = hx*a, q1 = hy*a, q2 = hz*a;
                const float* W = t101 + (u*16+v)*8;
                #pragma unroll
                for (int w = 0; w < 8; ++w) {
                    float ww = W[w];
                    o1[w*3+0] += q0*ww; o1[w*3+1] += q1*ww; o1[w*3+2] += q2*ww;
                }
            }
        }
        // (1,2,1): q = CEPS * (h1[u] x a2[v])
        #pragma unroll 1
        for (int u = 0; u < 8; ++u) {
            float hx = LD(16+u*3), hy = LD(16+u*3+1), hz = LD(16+u*3+2);
            #pragma unroll 1
            for (int v = 0; v < 8; ++v) {
                float ax = LD(104+v*3), ay = LD(104+v*3+1), az = LD(104+v*3+2);
                float q0 = CEPS*(hy*az - hz*ay);
                float q1 = CEPS*(hz*ax - hx*az);
                float q2 = CEPS*(hx*ay - hy*ax);
                const float* W = t121 + (u*8+v)*8;
                #pragma unroll
                for (int w = 0; w < 8; ++w) {
                    float ww = W[w];
                    o1[w*3+0] += q0*ww; o1[w*3+1] += q1*ww; o1[w*3+2] += q2*ww;
                }
            }
        }
        // (2,1,1): q = CEPS * (h2[u] x a1[v])
        #pragma unroll 1
        for (int u = 0; u < 8; ++u) {
            float hx = LD(40+u*3), hy = LD(40+u*3+1), hz = LD(40+u*3+2);
            #pragma unroll 1
            for (int v = 0; v < 8; ++v) {
                float ax = LD(80+v*3), ay = LD(80+v*3+1), az = LD(80+v*3+2);
                float q0 = CEPS*(hy*az - hz*ay);
                float q1 = CEPS*(hz*ax - hx*az);
                float q2 = CEPS*(hx*ay - hy*ax);
                const float* W = t211 + (u*8+v)*8;
                #pragma unroll
                for (int w = 0; w < 8; ++w) {
                    float ww = W[w];
                    o1[w*3+0] += q0*ww; o1[w*3+1] += q1*ww; o1[w*3+2] += q2*ww;
                }
            }
        }
        float4* o4 = (float4*)(out + n*64 + 16);
        #pragma unroll
        for (int i = 0; i < 6; ++i) {
            float4 v; v.x = o1[4*i]; v.y = o1[4*i+1]; v.z = o1[4*i+2]; v.w = o1[4*i+3];
            o4[i] = v;
        }
    }
    // ---- out irrep 2 (8x1e) ----
    {
        float o2[24];
        #pragma unroll
        for (int j = 0; j < 24; ++j) o2[j] = 0.f;
        // (0,2,2): q[k] = C1X * h0[u] * a2[v][k]
        #pragma unroll 1
        for (int u = 0; u < 16; ++u) {
            float hu = C1X * LD(u);
            #pragma unroll 1
            for (int v = 0; v < 8; ++v) {
                float q0 = hu*LD(104+v*3), q1 = hu*LD(104+v*3+1), q2 = hu*LD(104+v*3+2);
                const float* W = t022 + (u*8+v)*8;
                #pragma unroll
                for (int w = 0; w < 8; ++w) {
                    float ww = W[w];
                    o2[w*3+0] += q0*ww; o2[w*3+1] += q1*ww; o2[w*3+2] += q2*ww;
                }
            }
        }
        // (2,0,2): q[k] = C1X * h2[u][k] * a0[v]
        #pragma unroll 1
        for (int u = 0; u < 8; ++u) {
            float hx = LD(40+u*3), hy = LD(40+u*3+1), hz = LD(40+u*3+2);
            #pragma unroll 1
            for (int v = 0; v < 16; ++v) {
                float a = C1X * LD(64+v);
                float q0 = hx*a, q1 = hy*a, q2 = hz*a;
                const float* W = t202 + (u*16+v)*8;
                #pragma unroll
                for (int w = 0; w < 8; ++w) {
                    float ww = W[w];
                    o2[w*3+0] += q0*ww; o2[w*3+1] += q1*ww; o2[w*3+2] += q2*ww;
                }
            }
        }
        // (1,1,2): q = CEPS * (h1[u] x a1[v])
        #pragma unroll 1
        for (int u = 0; u < 8; ++u) {
            float hx = LD(16+u*3), hy = LD(16+u*3+1), hz = LD(16+u*3+2);
            #pragma unroll 1
            for (int v = 0; v < 8; ++v) {
                float ax = LD(80+v*3), ay = LD(80+v*3+1), az = LD(80+v*3+2);
                float q0 = CEPS*(hy*az - hz*ay);
                float q1 = CEPS*(hz*ax - hx*az);
                float q2 = CEPS*(hx*ay - hy*ax);
                const float* W = t112 + (u*8+v)*8;
                #pragma unroll
                for (int w = 0; w < 8; ++w) {
                    float ww = W[w];
                    o2[w*3+0] += q0*ww; o2[w*3+1] += q1*ww; o2[w*3+2] += q2*ww;
                }
            }
        }
        // (2,2,2): q = CEPS * (h2[u] x a2[v])
        #pragma unroll 1
        for (int u = 0; u < 8; ++u) {
            float hx = LD(40+u*3), hy = LD(40+u*3+1), hz = LD(40+u*3+2);
            #pragma unroll 1
            for (int v = 0; v < 8; ++v) {
                float ax = LD(104+v*3), ay = LD(104+v*3+1), az = LD(104+v*3+2);
                float q0 = CEPS*(hy*az - hz*ay);
                float q1 = CEPS*(hz*ax - hx*az);
                float q2 = CEPS*(hx*ay - hy*ax);
                const float* W = t222 + (u*8+v)*8;
                #pragma unroll
                for (int w = 0; w < 8; ++w) {
                    float ww = W[w];
                    o2[w*3+0] += q0*ww; o2[w*3+1] += q1*ww; o2[w*3+2] += q2*ww;
                }
            }
        }
        float4* o4 = (float4*)(out + n*64 + 40);
        #pragma unroll
        for (int i = 0; i < 6; ++i) {
            float4 v; v.x = o2[4*i]; v.y = o2[4*i+1]; v.z = o2[4*i+2]; v.w = o2[4*i+3];
            o4[i] = v;
        }
    }
    #undef LD
}

extern "C" void kernel_launch(void* const* d_in, const int* in_sizes, int n_in,
                              void* d_out, int out_size, void* d_ws, size_t ws_size,
                              hipStream_t stream) {
    const float* x    = (const float*)d_in[0];
    const float* lw0  = (const float*)d_in[1];
    const float* lw1  = (const float*)d_in[2];
    const float* lw2  = (const float*)d_in[3];
    const float* aw0  = (const float*)d_in[4];
    const float* aw1  = (const float*)d_in[5];
    const float* aw2  = (const float*)d_in[6];
    const float* t000 = (const float*)d_in[7];
    const float* t110 = (const float*)d_in[8];
    const float* t220 = (const float*)d_in[9];
    const float* t011 = (const float*)d_in[10];
    const float* t101 = (const float*)d_in[11];
    const float* t121 = (const float*)d_in[12];
    const float* t211 = (const float*)d_in[13];
    const float* t022 = (const float*)d_in[14];
    const float* t202 = (const float*)d_in[15];
    const float* t112 = (const float*)d_in[16];
    const float* t222 = (const float*)d_in[17];
    float* out = (float*)d_out;

    dim3 grid(NROWS / BLK), block(BLK);
    hipLaunchKernelGGL(e3nn_fwd, grid, block, 0, stream,
                       x, lw0, lw1, lw2, aw0, aw1, aw2,
                       t000, t110, t220, t011, t101, t121, t211,
                       t022, t202, t112, t222, out);
}

// Round 2
// 516.577 us; speedup vs baseline: 2.7008x; 2.7008x over previous
//
#include <hip/hip_runtime.h>
#include <hip/hip_bf16.h>
#include <math.h>

#define NROWS 524288
#define BLK 256
#define RPB 128          // rows per block
#define HSTR 136         // ha row stride in bf16 (16B-aligned, bank-safe)

// Path constants (verified round 1):
#define C000 0.051031036307982884f
#define C110 0.029462782549439483f
#define C1X  0.051031036307982884f
#define CEPS 0.036084391824351615f

typedef __attribute__((ext_vector_type(8))) short bf16x8;
typedef __attribute__((ext_vector_type(8))) unsigned short u16x8;
typedef __attribute__((ext_vector_type(4))) float f32x4;

#define MFMA(a, b, c) __builtin_amdgcn_mfma_f32_16x16x32_bf16(a, b, c, 0, 0, 0)

__device__ __forceinline__ float b2f(unsigned short u) {
    union { unsigned int u; float f; } c; c.u = ((unsigned int)u) << 16;
    return c.f;
}
__device__ __forceinline__ unsigned short f2b_rne(float f) {
    union { float f; unsigned int u; } c; c.f = f;
    unsigned int u = c.u;
    return (unsigned short)((u + 0x7fffu + ((u >> 16) & 1u)) >> 16);
}
// cheap pack: round-half-up (near-unbiased for random data), 2 ops
__device__ __forceinline__ short pkc(float f) {
    union { float f; unsigned int u; } c; c.f = f;
    return (short)((c.u + 0x8000u) >> 16);
}
__device__ __forceinline__ float sigm(float v) { return 1.0f / (1.0f + __expf(-v)); }

// LDS h/a layout per row (bf16, stride HSTR):
//  h0: e=0..15   h1: e=16+u*3+i   h2: e=40+u*3+i
//  a0: e=64..79  a1: e=80+v*3+i   a2: e=104+v*3+i
__global__ __launch_bounds__(BLK, 2) void e3nn_fwd(
    const float* __restrict__ x,
    const float* __restrict__ lw0, const float* __restrict__ lw1, const float* __restrict__ lw2,
    const float* __restrict__ aw0, const float* __restrict__ aw1, const float* __restrict__ aw2,
    const float* __restrict__ t000, const float* __restrict__ t110, const float* __restrict__ t220,
    const float* __restrict__ t011, const float* __restrict__ t101, const float* __restrict__ t121,
    const float* __restrict__ t211, const float* __restrict__ t022, const float* __restrict__ t202,
    const float* __restrict__ t112, const float* __restrict__ t222,
    float* __restrict__ out)
{
    __shared__ unsigned short ha[RPB * HSTR];
    const int t = threadIdx.x;
    const int lane = t & 63;
    const int wave = t >> 6;
    const long row0 = (long)blockIdx.x * RPB;

    // ============ Phase 0: B-fragments (weights) into registers ============
    // B layout for mfma_16x16x32: lane holds B[k = q*8+j][n = lane&15].
    const int nn = lane & 15;
    const int q = lane >> 4;
    bf16x8 w0f[12], w12f[12];
    {
        // W0: kk<256: t000[kk=u*16+v][n]*C000; [256,320): t110[u*8+v][n]*C110; [320,384): t220*C110
        #pragma unroll
        for (int mf = 0; mf < 8; ++mf) {
            const int kk = mf * 32 + q * 8;
            #pragma unroll
            for (int j = 0; j < 8; ++j)
                w0f[mf][j] = (short)f2b_rne(t000[(kk + j) * 16 + nn] * C000);
        }
        #pragma unroll
        for (int mf = 8; mf < 10; ++mf) {
            const int kk = (mf - 8) * 32 + q * 8;
            #pragma unroll
            for (int j = 0; j < 8; ++j)
                w0f[mf][j] = (short)f2b_rne(t110[(kk + j) * 16 + nn] * C110);
        }
        #pragma unroll
        for (int mf = 10; mf < 12; ++mf) {
            const int kk = (mf - 10) * 32 + q * 8;
            #pragma unroll
            for (int j = 0; j < 8; ++j)
                w0f[mf][j] = (short)f2b_rne(t220[(kk + j) * 16 + nn] * C110);
        }
        // W12: n<8 -> W1 (out1 paths), n>=8 -> W2 (out2 paths)
        const bool o2 = nn >= 8;
        const int n8 = nn & 7;
        #pragma unroll
        for (int mf = 0; mf < 4; ++mf) {         // kk = v*16+u : (0,1,1)/(0,2,2)
            #pragma unroll
            for (int j = 0; j < 8; ++j) {
                const int kk = mf * 32 + q * 8 + j;
                const int v = kk >> 4, u = kk & 15;
                const float val = o2 ? t022[u * 64 + v * 8 + n8] : t011[u * 64 + v * 8 + n8];
                w12f[mf][j] = (short)f2b_rne(val * C1X);
            }
        }
        #pragma unroll
        for (int mf = 4; mf < 8; ++mf) {         // kk-128 = u*16+v : (1,0,1)/(2,0,2)
            #pragma unroll
            for (int j = 0; j < 8; ++j) {
                const int kk = (mf - 4) * 32 + q * 8 + j;
                const int u = kk >> 4, v = kk & 15;
                const float val = o2 ? t202[u * 128 + v * 8 + n8] : t101[u * 128 + v * 8 + n8];
                w12f[mf][j] = (short)f2b_rne(val * C1X);
            }
        }
        #pragma unroll
        for (int mf = 8; mf < 10; ++mf) {        // kk-256 = u*8+v : (1,2,1)/(1,1,2)
            #pragma unroll
            for (int j = 0; j < 8; ++j) {
                const int kk = (mf - 8) * 32 + q * 8 + j;
                const float val = o2 ? t112[kk * 8 + n8] : t121[kk * 8 + n8];
                w12f[mf][j] = (short)f2b_rne(val * CEPS);
            }
        }
        #pragma unroll
        for (int mf = 10; mf < 12; ++mf) {       // kk-320 = u*8+v : (2,1,1)/(2,2,2)
            #pragma unroll
            for (int j = 0; j < 8; ++j) {
                const int kk = (mf - 10) * 32 + q * 8 + j;
                const float val = o2 ? t222[kk * 8 + n8] : t211[kk * 8 + n8];
                w12f[mf][j] = (short)f2b_rne(val * CEPS);
            }
        }
    }

    // ============ Phase 1: h / a -> LDS (2 threads per row) ============
    {
        const int row = t & (RPB - 1);
        const int half = t >> 7;                   // wave-uniform
        const float* xr = x + (row0 + row) * 64;
        const int hbase = row * HSTR;
        // l=0 (mul 16): this thread computes v = half*8 .. half*8+7
        {
            float xv[16];
            #pragma unroll
            for (int i = 0; i < 4; ++i) {
                float4 v4 = ((const float4*)xr)[i];
                xv[4*i] = v4.x; xv[4*i+1] = v4.y; xv[4*i+2] = v4.z; xv[4*i+3] = v4.w;
            }
            float hv[8], av[8];
            #pragma unroll
            for (int v = 0; v < 8; ++v) { hv[v] = 0.f; av[v] = 0.f; }
            #pragma unroll
            for (int u = 0; u < 16; ++u) {
                #pragma unroll
                for (int v = 0; v < 8; ++v) {
                    hv[v] += xv[u] * lw0[u * 16 + half * 8 + v];
                    av[v] += xv[u] * aw0[u * 16 + half * 8 + v];
                }
            }
            #pragma unroll
            for (int v = 0; v < 8; ++v) {
                const int vv = half * 8 + v;
                ha[hbase + vv] = f2b_rne(hv[v] * 0.25f);
                float a = av[v] * 0.25f;
                float nrm = fabsf(a);
                float den = (nrm == 0.f) ? 1.f : nrm;
                ha[hbase + 64 + vv] = f2b_rne(a * (sigm(nrm) / den));
            }
        }
        // l=1 blocks (mul 8): this thread computes v = half*4 .. half*4+3
        #pragma unroll 1
        for (int blk = 0; blk < 2; ++blk) {
            const float* xb = xr + 16 + blk * 24;
            const float* lw = blk ? lw2 : lw1;
            const float* aw = blk ? aw2 : aw1;
            float xv2[24];
            #pragma unroll
            for (int i = 0; i < 6; ++i) {
                float4 v4 = ((const float4*)xb)[i];
                xv2[4*i] = v4.x; xv2[4*i+1] = v4.y; xv2[4*i+2] = v4.z; xv2[4*i+3] = v4.w;
            }
            float hv2[12], av2[12];
            #pragma unroll
            for (int j = 0; j < 12; ++j) { hv2[j] = 0.f; av2[j] = 0.f; }
            #pragma unroll
            for (int u = 0; u < 8; ++u) {
                #pragma unroll
                for (int v = 0; v < 4; ++v) {
                    const float w1 = lw[u * 8 + half * 4 + v];
                    const float w2 = aw[u * 8 + half * 4 + v];
                    #pragma unroll
                    for (int i = 0; i < 3; ++i) {
                        hv2[v*3+i] += xv2[u*3+i] * w1;
                        av2[v*3+i] += xv2[u*3+i] * w2;
                    }
                }
            }
            const float s8 = 0.35355339059327373f;  // 1/sqrt(8)
            const int eh = 16 + blk * 24, ea = 80 + blk * 24;
            #pragma unroll
            for (int v = 0; v < 4; ++v) {
                const int vv = half * 4 + v;
                ha[hbase + eh + vv*3+0] = f2b_rne(hv2[v*3+0] * s8);
                ha[hbase + eh + vv*3+1] = f2b_rne(hv2[v*3+1] * s8);
                ha[hbase + eh + vv*3+2] = f2b_rne(hv2[v*3+2] * s8);
                float a0_ = av2[v*3+0]*s8, a1_ = av2[v*3+1]*s8, a2_ = av2[v*3+2]*s8;
                float nrm = sqrtf(a0_*a0_ + a1_*a1_ + a2_*a2_);
                float den = (nrm == 0.f) ? 1.f : nrm;
                float fac = sigm(nrm) / den;
                ha[hbase + ea + vv*3+0] = f2b_rne(a0_ * fac);
                ha[hbase + ea + vv*3+1] = f2b_rne(a1_ * fac);
                ha[hbase + ea + vv*3+2] = f2b_rne(a2_ * fac);
            }
        }
    }
    __syncthreads();

    // ============ Phase 2: MFMA tensor product ============
    // A layout: lane holds A[m = lane&15][k = q*8+j].
    const int m = lane & 15;
    const int qh = q >> 1;          // 0/1
    const int ql = (q & 1) * 8;     // 0/8

    #pragma unroll 1
    for (int gi = 0; gi < 2; ++gi) {
        const int grp = wave * 2 + gi;
        const long grow = row0 + grp * 16;

        // ---------- out0 tile: F0[16 rows x 384] @ W0 ----------
        {
            const int base = (grp * 16 + m) * HSTR;
            u16x8 a0v = *(const u16x8*)&ha[base + 64 + ql];
            unsigned short a1v[24], a2v[24];
            *(u16x8*)&a1v[0]  = *(const u16x8*)&ha[base + 80];
            *(u16x8*)&a1v[8]  = *(const u16x8*)&ha[base + 88];
            *(u16x8*)&a1v[16] = *(const u16x8*)&ha[base + 96];
            *(u16x8*)&a2v[0]  = *(const u16x8*)&ha[base + 104];
            *(u16x8*)&a2v[8]  = *(const u16x8*)&ha[base + 112];
            *(u16x8*)&a2v[16] = *(const u16x8*)&ha[base + 120];
            f32x4 acc = {0.f, 0.f, 0.f, 0.f};
            #pragma unroll
            for (int mf = 0; mf < 8; ++mf) {     // (0,0,0): k = u*16+v, h0[u]*a0[v]
                const int u = mf * 2 + qh;
                const float h = b2f(ha[base + u]);
                bf16x8 af;
                #pragma unroll
                for (int j = 0; j < 8; ++j) af[j] = pkc(h * b2f(a0v[j]));
                acc = MFMA(af, w0f[mf], acc);
            }
            #pragma unroll
            for (int mf = 8; mf < 12; ++mf) {    // (1,1,0)/(2,2,0): dot3
                const int u = ((mf < 10) ? (mf - 8) * 4 : (mf - 10) * 4) + q;
                const int he = (mf < 10) ? 16 : 40;
                const unsigned short* av = (mf < 10) ? a1v : a2v;
                const float hx = b2f(ha[base + he + u*3 + 0]);
                const float hy = b2f(ha[base + he + u*3 + 1]);
                const float hz = b2f(ha[base + he + u*3 + 2]);
                bf16x8 af;
                #pragma unroll
                for (int j = 0; j < 8; ++j)
                    af[j] = pkc(hx*b2f(av[3*j]) + hy*b2f(av[3*j+1]) + hz*b2f(av[3*j+2]));
                acc = MFMA(af, w0f[mf], acc);
            }
            #pragma unroll
            for (int r = 0; r < 4; ++r)
                out[(grow + q * 4 + r) * 64 + m] = acc[r];
        }

        // ---------- out1/out2 tiles: rows m<8 = F1k, m>=8 = F2k ----------
        const int m7 = m & 7;
        const bool iF2 = (m >= 8);
        #pragma unroll 1
        for (int g = 0; g < 2; ++g) {
            const int base = (grp * 16 + g * 8 + m7) * HSTR;
            u16x8 h0v = *(const u16x8*)&ha[base + ql];
            u16x8 a0v = *(const u16x8*)&ha[base + 64 + ql];
            unsigned short a1v[24], a2v[24];
            *(u16x8*)&a1v[0]  = *(const u16x8*)&ha[base + 80];
            *(u16x8*)&a1v[8]  = *(const u16x8*)&ha[base + 88];
            *(u16x8*)&a1v[16] = *(const u16x8*)&ha[base + 96];
            *(u16x8*)&a2v[0]  = *(const u16x8*)&ha[base + 104];
            *(u16x8*)&a2v[8]  = *(const u16x8*)&ha[base + 112];
            *(u16x8*)&a2v[16] = *(const u16x8*)&ha[base + 120];

            #pragma unroll
            for (int k = 0; k < 3; ++k) {
                const int k1 = (k == 2) ? 0 : k + 1;
                const int k2 = (k == 0) ? 2 : k - 1;
                f32x4 acc = {0.f, 0.f, 0.f, 0.f};
                // mf 0..3: kk = v*16+u -> h0[u] * a{1|2}[v][k]
                #pragma unroll
                for (int mf = 0; mf < 4; ++mf) {
                    const int v = mf * 2 + qh;
                    const float s = b2f(ha[base + (iF2 ? 104 : 80) + v * 3 + k]);
                    bf16x8 af;
                    #pragma unroll
                    for (int j = 0; j < 8; ++j) af[j] = pkc(s * b2f(h0v[j]));
                    acc = MFMA(af, w12f[mf], acc);
                }
                // mf 4..7: kk-128 = u*16+v -> h{1|2}[u][k] * a0[v]
                #pragma unroll
                for (int mf = 4; mf < 8; ++mf) {
                    const int u = (mf - 4) * 2 + qh;
                    const float s = b2f(ha[base + (iF2 ? 40 : 16) + u * 3 + k]);
                    bf16x8 af;
                    #pragma unroll
                    for (int j = 0; j < 8; ++j) af[j] = pkc(s * b2f(a0v[j]));
                    acc = MFMA(af, w12f[mf], acc);
                }
                // mf 8,9: kk-256 = u*8+v -> cross(h1[u], a{2|1}[v])[k]
                #pragma unroll
                for (int mf = 8; mf < 10; ++mf) {
                    const int u = (mf - 8) * 4 + q;
                    const float hk1 = b2f(ha[base + 16 + u*3 + k1]);
                    const float hk2 = b2f(ha[base + 16 + u*3 + k2]);
                    const unsigned short* av = iF2 ? a1v : a2v;
                    bf16x8 af;
                    #pragma unroll
                    for (int j = 0; j < 8; ++j)
                        af[j] = pkc(hk1 * b2f(av[3*j + k2]) - hk2 * b2f(av[3*j + k1]));
                    acc = MFMA(af, w12f[mf], acc);
                }
                // mf 10,11: kk-320 = u*8+v -> cross(h2[u], a{1|2}[v])[k]
                #pragma unroll
                for (int mf = 10; mf < 12; ++mf) {
                    const int u = (mf - 10) * 4 + q;
                    const float hk1 = b2f(ha[base + 40 + u*3 + k1]);
                    const float hk2 = b2f(ha[base + 40 + u*3 + k2]);
                    const unsigned short* av = iF2 ? a2v : a1v;
                    bf16x8 af;
                    #pragma unroll
                    for (int j = 0; j < 8; ++j)
                        af[j] = pkc(hk1 * b2f(av[3*j + k2]) - hk2 * b2f(av[3*j + k1]));
                    acc = MFMA(af, w12f[mf], acc);
                }
                // store: D rows q*4+r; q<2 -> out1 (cols n<8), q>=2 -> out2 (cols n>=8)
                if ((m >= 8) == (q >= 2)) {
                    const int obase = (q >= 2) ? 40 : 16;
                    const int rbase = (q & 1) * 4;
                    const int wc = m & 7;
                    #pragma unroll
                    for (int r = 0; r < 4; ++r)
                        out[(grow + g * 8 + rbase + r) * 64 + obase + wc * 3 + k] = acc[r];
                }
            }
        }
    }
}

extern "C" void kernel_launch(void* const* d_in, const int* in_sizes, int n_in,
                              void* d_out, int out_size, void* d_ws, size_t ws_size,
                              hipStream_t stream) {
    const float* x    = (const float*)d_in[0];
    const float* lw0  = (const float*)d_in[1];
    const float* lw1  = (const float*)d_in[2];
    const float* lw2  = (const float*)d_in[3];
    const float* aw0  = (const float*)d_in[4];
    const float* aw1  = (const float*)d_in[5];
    const float* aw2  = (const float*)d_in[6];
    const float* t000 = (const float*)d_in[7];
    const float* t110 = (const float*)d_in[8];
    const float* t220 = (const float*)d_in[9];
    const float* t011 = (const float*)d_in[10];
    const float* t101 = (const float*)d_in[11];
    const float* t121 = (const float*)d_in[12];
    const float* t211 = (const float*)d_in[13];
    const float* t022 = (const float*)d_in[14];
    const float* t202 = (const float*)d_in[15];
    const float* t112 = (const float*)d_in[16];
    const float* t222 = (const float*)d_in[17];
    float* out = (float*)d_out;

    dim3 grid(NROWS / RPB), block(BLK);
    hipLaunchKernelGGL(e3nn_fwd, grid, block, 0, stream,
                       x, lw0, lw1, lw2, aw0, aw1, aw2,
                       t000, t110, t220, t011, t101, t121, t211,
                       t022, t202, t112, t222, out);
}